// Round 5
// baseline (816.734 us; speedup 1.0000x reference)
//
#include <hip/hip_runtime.h>

#define CDIM 128
#define SCAN_BLK 512
#define BSHIFT 11
#define NBUCK 25        // ceil(50000 / 2048)
#define PART_EPB 2048   // edges per partition block

typedef __attribute__((ext_vector_type(8))) short short8;
typedef __attribute__((ext_vector_type(4))) float f32x4;

__device__ __forceinline__ unsigned short f2bf(float f) {
    unsigned int u = __float_as_uint(f);
    u = (u + 0x7FFF + ((u >> 16) & 1)) >> 16;  // RNE
    return (unsigned short)u;
}
__device__ __forceinline__ float bflo(unsigned int w) { return __uint_as_float(w << 16); }
__device__ __forceinline__ float bfhi(unsigned int w) { return __uint_as_float(w & 0xFFFF0000u); }

// ---------------- softmax over P=3 of d[3][128] -> dw[3][128] ----------------
__global__ void softmax_dw_kernel(const float* __restrict__ d, float* __restrict__ dw) {
    int c = threadIdx.x;
    float d0 = d[0 * CDIM + c], d1 = d[1 * CDIM + c], d2 = d[2 * CDIM + c];
    float m = fmaxf(d0, fmaxf(d1, d2));
    float e0 = expf(d0 - m), e1 = expf(d1 - m), e2 = expf(d2 - m);
    float inv = 1.0f / (e0 + e1 + e2);
    dw[0 * CDIM + c] = e0 * inv;
    dw[1 * CDIM + c] = e1 * inv;
    dw[2 * CDIM + c] = e2 * inv;
}

// ---------------- x fp32 -> bf16, padded rows zeroed ----------------
__global__ void conv_x_kernel(const float* __restrict__ x, unsigned short* __restrict__ x16,
                              int total, int padded_total) {
    int i8 = (blockIdx.x * blockDim.x + threadIdx.x) * 8;
    if (i8 >= padded_total) return;
    unsigned short o[8];
    if (i8 + 8 <= total) {
        float4 a = *reinterpret_cast<const float4*>(x + i8);
        float4 b = *reinterpret_cast<const float4*>(x + i8 + 4);
        o[0] = f2bf(a.x); o[1] = f2bf(a.y); o[2] = f2bf(a.z); o[3] = f2bf(a.w);
        o[4] = f2bf(b.x); o[5] = f2bf(b.y); o[6] = f2bf(b.z); o[7] = f2bf(b.w);
    } else {
        for (int j = 0; j < 8; ++j) o[j] = 0;
    }
    *reinterpret_cast<short8*>(x16 + i8) = *reinterpret_cast<short8*>(o);
}

// ---------------- Wk,Wq,Wv fp32 [3][128][128] -> w16 [hop][proj3][c][k] bf16 ----------------
__global__ void conv_w_kernel(const float* __restrict__ Wk, const float* __restrict__ Wq,
                              const float* __restrict__ Wv, unsigned short* __restrict__ w16) {
    int i = blockIdx.x * blockDim.x + threadIdx.x;  // over 3*3*16384
    if (i >= 3 * 3 * 16384) return;
    int hop = i / 49152;
    int r = i - hop * 49152;
    int pj = r >> 14;
    int el = r & 16383;
    const float* src = (pj == 0) ? Wk : (pj == 1) ? Wq : Wv;
    w16[i] = f2bf(src[(size_t)hop * 16384 + el]);
}

// ---------------- skip fusion: W'[c,k]=sum_p dw[p][c]*Wskip[p][c][k]; b'[c] ----------------
__global__ void prep_skip_kernel(const float* __restrict__ Wskip, const float* __restrict__ cbias,
                                 const float* __restrict__ hop_bias, const float* __restrict__ dw,
                                 unsigned short* __restrict__ wskip16, float* __restrict__ biasS) {
    int i = blockIdx.x * blockDim.x + threadIdx.x;
    if (i >= 16384) return;
    int c = i >> 7;
    float acc = dw[0 * CDIM + c] * Wskip[0 * 16384 + i] +
                dw[1 * CDIM + c] * Wskip[1 * 16384 + i] +
                dw[2 * CDIM + c] * Wskip[2 * 16384 + i];
    wskip16[i] = f2bf(acc);
    if ((i & 127) == 0) {
        float b = dw[0 * CDIM + c] * cbias[0 * CDIM + c] +
                  dw[1 * CDIM + c] * cbias[1 * CDIM + c] +
                  dw[2 * CDIM + c] * cbias[2 * CDIM + c];
        biasS[c] = b + hop_bias[c];
    }
}

// ---------------- degree count, all 3 hops ----------------
__global__ void deg3_kernel(const int* __restrict__ ei0, const int* __restrict__ ei1,
                            const int* __restrict__ ei2, int* __restrict__ deg_all, int E, int N) {
    int e = blockIdx.x * blockDim.x + threadIdx.x;
    if (e >= E) return;
    int p = blockIdx.y;
    const int* ei = (p == 0) ? ei0 : (p == 1) ? ei1 : ei2;
    atomicAdd(&deg_all[p * N + ei[E + e]], 1);
}

// ---------------- scan A: per-block totals ----------------
__global__ __launch_bounds__(SCAN_BLK) void scanA_kernel(const int* __restrict__ deg, int* __restrict__ bsum, int n) {
    __shared__ int s[SCAN_BLK];
    int t = threadIdx.x;
    int idx = blockIdx.x * SCAN_BLK + t;
    s[t] = (idx < n) ? deg[idx] : 0;
    __syncthreads();
    for (int off = SCAN_BLK / 2; off > 0; off >>= 1) {
        if (t < off) s[t] += s[t + off];
        __syncthreads();
    }
    if (t == 0) bsum[blockIdx.x] = s[0];
}

// ---------------- scan B: exclusive scan of block sums ----------------
__global__ void scanB_kernel(int* __restrict__ bsum, int nb) {
    __shared__ int s[SCAN_BLK];
    int t = threadIdx.x;
    if (t < nb) s[t] = bsum[t];
    __syncthreads();
    if (t == 0) {
        int run = 0;
        for (int i = 0; i < nb; ++i) { int v = s[i]; s[i] = run; run += v; }
    }
    __syncthreads();
    if (t < nb) bsum[t] = s[t];
}

// ---------------- scan C: exclusive scan + cursor + dinv ----------------
__global__ __launch_bounds__(SCAN_BLK) void scanC_kernel(const int* __restrict__ deg, const int* __restrict__ bsum,
                                                         int* __restrict__ offs, int* __restrict__ cursor,
                                                         float* __restrict__ dinv, int n, int Etot) {
    __shared__ int s[SCAN_BLK];
    int t = threadIdx.x;
    int idx = blockIdx.x * SCAN_BLK + t;
    int v = (idx < n) ? deg[idx] : 0;
    s[t] = v;
    __syncthreads();
    for (int off = 1; off < SCAN_BLK; off <<= 1) {
        int a = (t >= off) ? s[t - off] : 0;
        __syncthreads();
        s[t] += a;
        __syncthreads();
    }
    if (idx < n) {
        int ex = s[t] - v + bsum[blockIdx.x];
        offs[idx] = ex;
        cursor[idx] = ex;
        dinv[idx] = v > 0 ? rsqrtf((float)v) : 0.0f;
    }
    if (idx == n - 1) offs[n] = Etot;
}

// ---------------- init bucket cursors: bcur[p][b] = offs[p*N + b*2048] (absolute) ----------------
__global__ void initbcur_kernel(const int* __restrict__ offs_all, int* __restrict__ bcur, int N) {
    int i = threadIdx.x;  // 0..74
    if (i >= 3 * NBUCK) return;
    int p = i / NBUCK;
    int b = i - p * NBUCK;
    bcur[i] = offs_all[(size_t)p * N + (b << BSHIFT)];
}

// ---------------- P2: partition edges into node-range buckets (locality-friendly) ----------------
// record: {(col<<16)|row, norm}; positions are absolute in [0, 3E)
__global__ __launch_bounds__(256) void partition3_kernel(
    const int* __restrict__ ei0, const int* __restrict__ ei1, const int* __restrict__ ei2,
    const float* __restrict__ ew0, const float* __restrict__ ew1, const float* __restrict__ ew2,
    const float* __restrict__ dinv_all, int* __restrict__ bcur,
    int2* __restrict__ etmp, int E, int N) {
    int p = blockIdx.y;
    const int* ei = (p == 0) ? ei0 : (p == 1) ? ei1 : ei2;
    const float* ew = (p == 0) ? ew0 : (p == 1) ? ew1 : ew2;
    __shared__ int hist[NBUCK], gbase[NBUCK];
    int t = threadIdx.x;
    if (t < NBUCK) hist[t] = 0;
    __syncthreads();
    int e0 = blockIdx.x * PART_EPB;
    int cnt = min(PART_EPB, E - e0);
    int rowv[8], colv[8], ordv[8], bkv[8];
    float nrmv[8];
#pragma unroll
    for (int i = 0; i < 8; ++i) {
        int li = i * 256 + t;
        if (li < cnt) {
            int e = e0 + li;
            int r = ei[e];
            int c = ei[E + e];
            rowv[i] = r; colv[i] = c;
            nrmv[i] = dinv_all[(size_t)p * N + r] * dinv_all[(size_t)p * N + c] * ew[e];
            bkv[i] = c >> BSHIFT;
            ordv[i] = atomicAdd(&hist[bkv[i]], 1);
        } else {
            bkv[i] = -1;
        }
    }
    __syncthreads();
    if (t < NBUCK) gbase[t] = atomicAdd(&bcur[p * NBUCK + t], hist[t]);
    __syncthreads();
#pragma unroll
    for (int i = 0; i < 8; ++i) {
        if (bkv[i] >= 0) {
            int pos = gbase[bkv[i]] + ordv[i];
            etmp[pos] = make_int2((colv[i] << 16) | rowv[i], __float_as_int(nrmv[i]));
        }
    }
}

// ---------------- P3: within-bucket CSR placement (writes stay in ~256KB window) ----------------
__global__ __launch_bounds__(256) void place3_kernel(
    const int2* __restrict__ etmp, const int* __restrict__ offs_all,
    int* __restrict__ cursor, int2* __restrict__ edata, int E, int N) {
    int p = blockIdx.y;
    int b = blockIdx.x >> 2;
    int slice = blockIdx.x & 3;
    int node0 = b << BSHIFT;
    if (node0 >= N) return;
    int node1 = node0 + (1 << BSHIFT);
    int start = offs_all[(size_t)p * N + node0];
    int end = (node1 >= N) ? offs_all[(size_t)p * N + N] /* == (p+1)*E via next hop base / total */
                           : offs_all[(size_t)p * N + node1];
    int mycnt = end - start;
    int s0 = start + (int)(((long long)mycnt * slice) >> 2);
    int s1 = start + (int)(((long long)mycnt * (slice + 1)) >> 2);
    for (int j = s0 + threadIdx.x; j < s1; j += 256) {
        int2 rec = etmp[j];
        int col = ((unsigned int)rec.x) >> 16;
        int row = rec.x & 0xFFFF;
        int pos = atomicAdd(&cursor[(size_t)p * N + col], 1);
        edata[pos] = make_int2(row, rec.y);
    }
}

// ---------------- bf16 MFMA GEMM: proj 0,1,2 = k,q,v ; proj 3 = fused skip -> out ----------------
__global__ __launch_bounds__(256) void gemm_mfma_kernel(
    const unsigned short* __restrict__ x16, const unsigned short* __restrict__ w3,
    const unsigned short* __restrict__ wskip16,
    const float* __restrict__ b0, const float* __restrict__ b1, const float* __restrict__ b2,
    const float* __restrict__ biasS,
    unsigned short* __restrict__ kbuf, unsigned short* __restrict__ qv,
    float* __restrict__ out, int N) {
    const int proj = blockIdx.y;
    const int row0 = blockIdx.x * 128;
    const int tid = threadIdx.x;
    const int w = tid >> 6;
    const int lane = tid & 63;
    const int wr = w >> 1;
    const int wc = w & 1;
    const int l15 = lane & 15;
    const int lg = lane >> 4;

    const unsigned short* wp = (proj == 3) ? wskip16 : w3 + (size_t)proj * 16384;

    f32x4 acc[4][4];
#pragma unroll
    for (int m = 0; m < 4; ++m)
#pragma unroll
        for (int n = 0; n < 4; ++n) acc[m][n] = (f32x4){0.f, 0.f, 0.f, 0.f};

#pragma unroll
    for (int ks = 0; ks < 4; ++ks) {
        const int k0 = ks * 32 + lg * 8;
        short8 a[4], b[4];
#pragma unroll
        for (int m = 0; m < 4; ++m) {
            int row = row0 + wr * 64 + m * 16 + l15;
            a[m] = *reinterpret_cast<const short8*>(x16 + (size_t)row * CDIM + k0);
        }
#pragma unroll
        for (int n = 0; n < 4; ++n) {
            int col = wc * 64 + n * 16 + l15;
            b[n] = *reinterpret_cast<const short8*>(wp + (size_t)col * CDIM + k0);
        }
#pragma unroll
        for (int m = 0; m < 4; ++m)
#pragma unroll
            for (int n = 0; n < 4; ++n)
                acc[m][n] = __builtin_amdgcn_mfma_f32_16x16x32_bf16(a[m], b[n], acc[m][n], 0, 0, 0);
    }

    const float* bias = (proj == 3) ? biasS : (proj == 0) ? b0 : (proj == 1) ? b1 : b2;
#pragma unroll
    for (int n = 0; n < 4; ++n) {
        int col = wc * 64 + n * 16 + l15;
        float bb = bias[col];
#pragma unroll
        for (int m = 0; m < 4; ++m) {
#pragma unroll
            for (int r = 0; r < 4; ++r) {
                int row = row0 + wr * 64 + m * 16 + lg * 4 + r;
                if (row < N) {
                    float val = acc[m][n][r] + bb;
                    if (proj == 3) {
                        out[(size_t)row * CDIM + col] = val;
                    } else if (proj == 0) {
                        kbuf[(size_t)row * CDIM + col] = f2bf(val);
                    } else if (proj == 1) {
                        qv[(size_t)row * 2 * CDIM + 2 * col] = f2bf(val);
                    } else {
                        qv[(size_t)row * 2 * CDIM + 2 * col + 1] = f2bf(val);
                    }
                }
            }
        }
    }
}

// ---------------- gather: one wave per node, 8-deep ILP on qv loads ----------------
__device__ __forceinline__ void edge_acc(unsigned int wx, unsigned int wy, float nrm,
                                         float k0, float k1, float& ax, float& ay) {
    float q0 = bflo(wx), v0 = bfhi(wx);
    float q1 = bflo(wy), v1 = bfhi(wy);
    ax = fmaf(nrm / (1.0f + __expf(-(k0 + q0))), v0, ax);
    ay = fmaf(nrm / (1.0f + __expf(-(k1 + q1))), v1, ay);
}

__global__ __launch_bounds__(256) void gather_kernel(
    const int2* __restrict__ edata, const int* __restrict__ offs,
    const unsigned short* __restrict__ kbuf, const unsigned short* __restrict__ qv,
    const float* __restrict__ dwp, float* __restrict__ out, int N) {
    int node = blockIdx.x * 4 + (threadIdx.x >> 6);
    if (node >= N) return;
    int lane = threadIdx.x & 63;
    int start = offs[node];
    int end = offs[node + 1];
    unsigned int kw = *reinterpret_cast<const unsigned int*>(kbuf + (size_t)node * CDIM + lane * 2);
    float k0 = bflo(kw), k1 = bfhi(kw);
    float ax = 0.f, ay = 0.f;

    for (int chunk = start; chunk < end; chunk += 64) {
        int cnt = min(64, end - chunk);
        int2 meta = make_int2(0, 0);
        if (chunk + lane < end) meta = edata[chunk + lane];
        int j = 0;
        for (; j + 8 <= cnt; j += 8) {
            uint2 w[8];
            float nn[8];
#pragma unroll
            for (int u = 0; u < 8; ++u) {
                int r = __shfl(meta.x, j + u);
                nn[u] = __int_as_float(__shfl(meta.y, j + u));
                w[u] = *reinterpret_cast<const uint2*>(qv + (size_t)r * 2 * CDIM + lane * 4);
            }
#pragma unroll
            for (int u = 0; u < 8; ++u) edge_acc(w[u].x, w[u].y, nn[u], k0, k1, ax, ay);
        }
        for (; j < cnt; ++j) {
            int r = __shfl(meta.x, j);
            float nn = __int_as_float(__shfl(meta.y, j));
            uint2 ww = *reinterpret_cast<const uint2*>(qv + (size_t)r * 2 * CDIM + lane * 4);
            edge_acc(ww.x, ww.y, nn, k0, k1, ax, ay);
        }
    }

    float2 dd = *reinterpret_cast<const float2*>(dwp + lane * 2);
    float2* op = reinterpret_cast<float2*>(out + (size_t)node * CDIM + lane * 2);
    float2 o = *op;
    o.x += ax * dd.x;
    o.y += ay * dd.y;
    *op = o;
}

extern "C" void kernel_launch(void* const* d_in, const int* in_sizes, int n_in,
                              void* d_out, int out_size, void* d_ws, size_t ws_size,
                              hipStream_t stream) {
    const float* x = (const float*)d_in[0];
    const int* ei0 = (const int*)d_in[1];
    const int* ei1 = (const int*)d_in[2];
    const int* ei2 = (const int*)d_in[3];
    const float* ew0 = (const float*)d_in[4];
    const float* ew1 = (const float*)d_in[5];
    const float* ew2 = (const float*)d_in[6];
    const float* Wk = (const float*)d_in[7];
    const float* bk = (const float*)d_in[8];
    const float* Wq = (const float*)d_in[9];
    const float* bq = (const float*)d_in[10];
    const float* Wv = (const float*)d_in[11];
    const float* bv = (const float*)d_in[12];
    const float* Wskip = (const float*)d_in[13];
    const float* cbias = (const float*)d_in[14];
    const float* d = (const float*)d_in[15];
    const float* hop_bias = (const float*)d_in[16];
    float* out = (float*)d_out;

    const int N = in_sizes[0] / CDIM;  // 50000
    const int E = in_sizes[4];         // 800000
    const int Npad = (N + 127) & ~127;
    const int n3 = 3 * N;
    const int nb = (n3 + SCAN_BLK - 1) / SCAN_BLK;

    // workspace layout
    char* wsp = (char*)d_ws;
    float* dw = (float*)wsp;                     wsp += 3 * CDIM * sizeof(float);
    float* biasS = (float*)wsp;                  wsp += CDIM * sizeof(float);
    unsigned short* x16 = (unsigned short*)wsp;  wsp += (size_t)Npad * CDIM * sizeof(unsigned short);
    unsigned short* w16 = (unsigned short*)wsp;  wsp += (size_t)3 * 3 * 16384 * sizeof(unsigned short);
    unsigned short* wskip16 = (unsigned short*)wsp; wsp += (size_t)16384 * sizeof(unsigned short);
    unsigned short* kbuf = (unsigned short*)wsp; wsp += (size_t)N * CDIM * sizeof(unsigned short);
    unsigned short* qv = (unsigned short*)wsp;   wsp += (size_t)N * 2 * CDIM * sizeof(unsigned short);
    int* deg_all = (int*)wsp;                    wsp += (size_t)n3 * sizeof(int);
    float* dinv_all = (float*)wsp;               wsp += (size_t)n3 * sizeof(float);
    int* offs_all = (int*)wsp;                   wsp += (size_t)(n3 + 4) * sizeof(int);
    int* cursor = (int*)wsp;                     wsp += (size_t)n3 * sizeof(int);
    int* bsum = (int*)wsp;                       wsp += SCAN_BLK * sizeof(int);
    int* bcur = (int*)wsp;                       wsp += 128 * sizeof(int);
    int2* etmp = (int2*)wsp;                     wsp += (size_t)3 * E * sizeof(int2);
    int2* edata = (int2*)wsp;                    wsp += (size_t)3 * E * sizeof(int2);

    softmax_dw_kernel<<<1, CDIM, 0, stream>>>(d, dw);
    conv_x_kernel<<<(Npad * CDIM / 8 + 255) / 256, 256, 0, stream>>>(x, x16, N * CDIM, Npad * CDIM);
    conv_w_kernel<<<(3 * 3 * 16384 + 255) / 256, 256, 0, stream>>>(Wk, Wq, Wv, w16);
    prep_skip_kernel<<<(16384 + 255) / 256, 256, 0, stream>>>(Wskip, cbias, hop_bias, dw, wskip16, biasS);

    hipMemsetAsync(deg_all, 0, (size_t)n3 * sizeof(int), stream);
    deg3_kernel<<<dim3((E + 511) / 512, 3), 512, 0, stream>>>(ei0, ei1, ei2, deg_all, E, N);
    scanA_kernel<<<nb, SCAN_BLK, 0, stream>>>(deg_all, bsum, n3);
    scanB_kernel<<<1, SCAN_BLK, 0, stream>>>(bsum, nb);
    scanC_kernel<<<nb, SCAN_BLK, 0, stream>>>(deg_all, bsum, offs_all, cursor, dinv_all, n3, 3 * E);
    initbcur_kernel<<<1, 128, 0, stream>>>(offs_all, bcur, N);
    partition3_kernel<<<dim3((E + PART_EPB - 1) / PART_EPB, 3), 256, 0, stream>>>(
        ei0, ei1, ei2, ew0, ew1, ew2, dinv_all, bcur, etmp, E, N);
    place3_kernel<<<dim3(NBUCK * 4, 3), 256, 0, stream>>>(etmp, offs_all, cursor, edata, E, N);

    const int gemm_blocks = (Npad + 127) / 128;
    for (int p = 0; p < 3; ++p) {
        gemm_mfma_kernel<<<dim3(gemm_blocks, p == 0 ? 4 : 3), 256, 0, stream>>>(
            x16, w16 + (size_t)p * 3 * 16384, wskip16,
            bk + (size_t)p * CDIM, bq + (size_t)p * CDIM, bv + (size_t)p * CDIM, biasS,
            kbuf, qv, out, N);
        gather_kernel<<<(N + 3) / 4, 256, 0, stream>>>(
            edata, offs_all + (size_t)p * N, kbuf, qv, dw + (size_t)p * CDIM, out, N);
    }
}